// Round 1
// baseline (26.563 us; speedup 1.0000x reference)
//
#include <hip/hip_runtime.h>

#define NB 1024
#define NT 256
// NB*NT*4 = 1048576 = B exactly; each thread handles 4 consecutive samples.

__device__ __forceinline__ float bce_f(float l, float t) {
    // max(l,0) - l*t + log1p(exp(-|l|))
    float e = __expf(-fabsf(l));
    return fmaxf(l, 0.0f) - l * t + __logf(1.0f + e);
}

__device__ __forceinline__ float z_from(float s, float n) {
    // 1.0f if sigmoid(s) > n else 0.0f   (sigmoid(s)>n  <=>  1-n > n*exp(-s))
    float e = __expf(-s);
    return (1.0f - n > n * e) ? 1.0f : 0.0f;
}

__global__ __launch_bounds__(NT) void wake_main(
    const float* __restrict__ y1, const float* __restrict__ y2,
    const float* __restrict__ n1, const float* __restrict__ n2,
    const float* __restrict__ n3, const float* __restrict__ n4,
    const float* __restrict__ i0w1, const float* __restrict__ i0b1,
    const float* __restrict__ i0w2, const float* __restrict__ i0b2,
    const float* __restrict__ i1w1, const float* __restrict__ i1b1,
    const float* __restrict__ i1w2, const float* __restrict__ i1b2,
    const float* __restrict__ i2w1, const float* __restrict__ i2b1,
    const float* __restrict__ i2w2, const float* __restrict__ i2b2,
    const float* __restrict__ i3w1, const float* __restrict__ i3b1,
    const float* __restrict__ i3w2, const float* __restrict__ i3b2,
    const float* __restrict__ g1w1, const float* __restrict__ g1b1,
    const float* __restrict__ g1w2, const float* __restrict__ g1b2,
    const float* __restrict__ g2w1, const float* __restrict__ g2b1,
    const float* __restrict__ g2w2, const float* __restrict__ g2b2,
    const float* __restrict__ g3w1, const float* __restrict__ g3b1,
    const float* __restrict__ g3w2, const float* __restrict__ g3b2,
    const float* __restrict__ g4w1, const float* __restrict__ g4b1,
    const float* __restrict__ g4w2, const float* __restrict__ g4b2,
    const float* __restrict__ g5w1, const float* __restrict__ g5b1,
    const float* __restrict__ g5w2, const float* __restrict__ g5b2,
    const float* __restrict__ g0w,
    float2* __restrict__ partials)
{
    // Binary-input MLP tables: 5 MLPs (inf3,g1,g2,g4,g5), inputs z in {0,1}^2.
    __shared__ float lds_eval[5][4][2];  // [mlp][combo c: z0=c&1,z1=c>>1][out k]
    __shared__ float lds_coef[40];       // [out o = m*2+k][4 coeffs]

    const int tid = threadIdx.x;
    const int g = blockIdx.x * NT + tid;

    // --- issue all global vector loads early (10 x float4 = 160B/thread) ---
    const float4 vy1  = reinterpret_cast<const float4*>(y1)[g];
    const float4 vy2  = reinterpret_cast<const float4*>(y2)[g];
    const float4 n1lo = reinterpret_cast<const float4*>(n1)[2*g];
    const float4 n1hi = reinterpret_cast<const float4*>(n1)[2*g+1];
    const float4 n2lo = reinterpret_cast<const float4*>(n2)[2*g];
    const float4 n2hi = reinterpret_cast<const float4*>(n2)[2*g+1];
    const float4 n3lo = reinterpret_cast<const float4*>(n3)[2*g];
    const float4 n3hi = reinterpret_cast<const float4*>(n3)[2*g+1];
    const float4 n4lo = reinterpret_cast<const float4*>(n4)[2*g];
    const float4 n4hi = reinterpret_cast<const float4*>(n4)[2*g+1];

    // --- prologue: evaluate the 5 binary-input MLPs at all 4 corners ---
    if (tid < 20) {
        const int m = tid >> 2, c = tid & 3;
        const float z0 = (float)(c & 1), z1f = (float)(c >> 1);
        const float *w1, *bb1, *w2, *bb2; int dout;
        switch (m) {
            case 0:  w1 = i3w1; bb1 = i3b1; w2 = i3w2; bb2 = i3b2; dout = 2; break;
            case 1:  w1 = g1w1; bb1 = g1b1; w2 = g1w2; bb2 = g1b2; dout = 2; break;
            case 2:  w1 = g2w1; bb1 = g2b1; w2 = g2w2; bb2 = g2b2; dout = 1; break;
            case 3:  w1 = g4w1; bb1 = g4b1; w2 = g4w2; bb2 = g4b2; dout = 2; break;
            default: w1 = g5w1; bb1 = g5b1; w2 = g5w2; bb2 = g5b2; dout = 1; break;
        }
        float o0 = bb2[0];
        float o1 = (dout == 2) ? bb2[1] : 0.0f;
        #pragma unroll
        for (int j = 0; j < 8; ++j) {
            float h = fmaxf(bb1[j] + z0 * w1[j] + z1f * w1[8 + j], 0.0f);
            o0 += h * w2[j * dout];
            if (dout == 2) o1 += h * w2[j * 2 + 1];
        }
        lds_eval[m][c][0] = o0;
        lds_eval[m][c][1] = o1;
    }
    __syncthreads();
    if (tid < 10) {
        const int m = tid >> 1, k = tid & 1;
        const float f00 = lds_eval[m][0][k], f10 = lds_eval[m][1][k];
        const float f01 = lds_eval[m][2][k], f11 = lds_eval[m][3][k];
        lds_coef[tid * 4 + 0] = f00;
        lds_coef[tid * 4 + 1] = f10 - f00;
        lds_coef[tid * 4 + 2] = f01 - f00;
        lds_coef[tid * 4 + 3] = f11 - f10 - f01 + f00;
    }
    __syncthreads();

    const float l40 = g0w[0], l41 = g0w[1];

    const float Y1a[4] = {vy1.x, vy1.y, vy1.z, vy1.w};
    const float Y2a[4] = {vy2.x, vy2.y, vy2.z, vy2.w};
    const float N1a[8] = {n1lo.x, n1lo.y, n1lo.z, n1lo.w, n1hi.x, n1hi.y, n1hi.z, n1hi.w};
    const float N2a[8] = {n2lo.x, n2lo.y, n2lo.z, n2lo.w, n2hi.x, n2hi.y, n2hi.z, n2hi.w};
    const float N3a[8] = {n3lo.x, n3lo.y, n3lo.z, n3lo.w, n3hi.x, n3hi.y, n3hi.z, n3hi.w};
    const float N4a[8] = {n4lo.x, n4lo.y, n4lo.z, n4lo.w, n4hi.x, n4hi.y, n4hi.z, n4hi.w};

    float lz = 0.0f, ly = 0.0f;
    #pragma unroll
    for (int s = 0; s < 4; ++s) {
        const float Y1 = Y1a[s], Y2 = Y2a[s];
        // inf0([y1,y2]) -> s1 (2 logits)
        float s10 = i0b2[0], s11 = i0b2[1];
        #pragma unroll
        for (int j = 0; j < 8; ++j) {
            float h = fmaxf(i0b1[j] + Y1 * i0w1[j] + Y2 * i0w1[8 + j], 0.0f);
            s10 += h * i0w2[2 * j]; s11 += h * i0w2[2 * j + 1];
        }
        const float z10 = z_from(s10, N1a[2 * s]);
        const float z11 = z_from(s11, N1a[2 * s + 1]);
        // inf1([y2,z1]) -> s2
        float s20 = i1b2[0], s21 = i1b2[1];
        #pragma unroll
        for (int j = 0; j < 8; ++j) {
            float h = fmaxf(i1b1[j] + Y2 * i1w1[j] + z10 * i1w1[8 + j] + z11 * i1w1[16 + j], 0.0f);
            s20 += h * i1w2[2 * j]; s21 += h * i1w2[2 * j + 1];
        }
        const float z20 = z_from(s20, N2a[2 * s]);
        const float z21 = z_from(s21, N2a[2 * s + 1]);
        // inf2(y2) -> s3
        float s30 = i2b2[0], s31 = i2b2[1];
        #pragma unroll
        for (int j = 0; j < 8; ++j) {
            float h = fmaxf(i2b1[j] + Y2 * i2w1[j], 0.0f);
            s30 += h * i2w2[2 * j]; s31 += h * i2w2[2 * j + 1];
        }
        const float z30 = z_from(s30, N3a[2 * s]);
        const float z31 = z_from(s31, N3a[2 * s + 1]);
        // inf3(z3) -> s4 via table coefficients
        const float p3 = z30 * z31;
        const float s40 = lds_coef[0] + lds_coef[1] * z30 + lds_coef[2] * z31 + lds_coef[3] * p3;
        const float s41 = lds_coef[4] + lds_coef[5] * z30 + lds_coef[6] * z31 + lds_coef[7] * p3;
        const float z40 = z_from(s40, N4a[2 * s]);
        const float z41 = z_from(s41, N4a[2 * s + 1]);
        const float p4 = z40 * z41;
        // l3 = g1(z4)
        const float l30 = lds_coef[8]  + lds_coef[9]  * z40 + lds_coef[10] * z41 + lds_coef[11] * p4;
        const float l31 = lds_coef[12] + lds_coef[13] * z40 + lds_coef[14] * z41 + lds_coef[15] * p4;
        // muy2 = g2(z3)
        const float muy2 = lds_coef[16] + lds_coef[17] * z30 + lds_coef[18] * z31 + lds_coef[19] * p3;
        // l2 = g3(y2) (full MLP, continuous input)
        float l20 = g3b2[0], l21 = g3b2[1];
        #pragma unroll
        for (int j = 0; j < 8; ++j) {
            float h = fmaxf(g3b1[j] + Y2 * g3w1[j], 0.0f);
            l20 += h * g3w2[2 * j]; l21 += h * g3w2[2 * j + 1];
        }
        // l1 = g4(z2)
        const float p2 = z20 * z21;
        const float l10 = lds_coef[24] + lds_coef[25] * z20 + lds_coef[26] * z21 + lds_coef[27] * p2;
        const float l11 = lds_coef[28] + lds_coef[29] * z20 + lds_coef[30] * z21 + lds_coef[31] * p2;
        // muy1 = g5(z1)
        const float p1 = z10 * z11;
        const float muy1 = lds_coef[32] + lds_coef[33] * z10 + lds_coef[34] * z11 + lds_coef[35] * p1;

        lz += bce_f(l10, z10) + bce_f(l11, z11)
            + bce_f(l20, z20) + bce_f(l21, z21)
            + bce_f(l30, z30) + bce_f(l31, z31)
            - l40 * z40 - l41 * z41;          // variable part of bce(l4, z4)
        const float d1 = Y1 - muy1, d2 = Y2 - muy2;
        ly += 2.0f * (d1 * d1) + 2.0f * (d2 * d2);
    }

    // --- wave + block reduction, one float2 partial per block ---
    #pragma unroll
    for (int off = 32; off > 0; off >>= 1) {
        lz += __shfl_down(lz, off);
        ly += __shfl_down(ly, off);
    }
    __shared__ float2 wsum[NT / 64];
    const int lane = tid & 63, wid = tid >> 6;
    if (lane == 0) wsum[wid] = make_float2(lz, ly);
    __syncthreads();
    if (tid == 0) {
        float a = 0.0f, b = 0.0f;
        #pragma unroll
        for (int w = 0; w < NT / 64; ++w) { a += wsum[w].x; b += wsum[w].y; }
        partials[blockIdx.x] = make_float2(a, b);
    }
}

__global__ __launch_bounds__(256) void wake_reduce(
    const float2* __restrict__ partials, const float* __restrict__ g0w,
    float* __restrict__ out)
{
    const int tid = threadIdx.x;
    float lz = 0.0f, ly = 0.0f;
    #pragma unroll
    for (int i = 0; i < NB / 256; ++i) {
        float2 p = partials[tid + i * 256];
        lz += p.x; ly += p.y;
    }
    #pragma unroll
    for (int off = 32; off > 0; off >>= 1) {
        lz += __shfl_down(lz, off);
        ly += __shfl_down(ly, off);
    }
    __shared__ float2 wsum[4];
    const int lane = tid & 63, wid = tid >> 6;
    if (lane == 0) wsum[wid] = make_float2(lz, ly);
    __syncthreads();
    if (tid == 0) {
        float a = 0.0f, b = 0.0f;
        #pragma unroll
        for (int w = 0; w < 4; ++w) { a += wsum[w].x; b += wsum[w].y; }
        const float l40 = g0w[0], l41 = g0w[1];
        // constant part of bce(l4, z4), per sample
        const float C4 = fmaxf(l40, 0.0f) + __logf(1.0f + __expf(-fabsf(l40)))
                       + fmaxf(l41, 0.0f) + __logf(1.0f + __expf(-fabsf(l41)));
        const float inv = 1.0f / 1048576.0f;
        const float loss_z = a * inv + C4;
        // per-sample const of -2 * Normal.logprob: 2*(_LOG_STD + _HALF_LOG_2PI)
        const float loss_y = b * inv + 0.4515827052894548f;
        out[0] = loss_z + loss_y;
        out[1] = loss_z;
        out[2] = loss_y;
    }
}

extern "C" void kernel_launch(void* const* d_in, const int* in_sizes, int n_in,
                              void* d_out, int out_size, void* d_ws, size_t ws_size,
                              hipStream_t stream) {
    const float* p[43];
    for (int i = 0; i < 43; ++i) p[i] = (const float*)d_in[i];
    float2* partials = (float2*)d_ws;
    wake_main<<<NB, NT, 0, stream>>>(
        p[0], p[1], p[2], p[3], p[4], p[5],
        p[6], p[7], p[8], p[9],
        p[10], p[11], p[12], p[13],
        p[14], p[15], p[16], p[17],
        p[18], p[19], p[20], p[21],
        p[22], p[23], p[24], p[25],
        p[26], p[27], p[28], p[29],
        p[30], p[31], p[32], p[33],
        p[34], p[35], p[36], p[37],
        p[38], p[39], p[40], p[41],
        p[42], partials);
    wake_reduce<<<1, 256, 0, stream>>>(partials, p[42], (float*)d_out);
}